// Round 1
// 1354.496 us; speedup vs baseline: 1.0079x; 1.0079x over previous
//
#include <hip/hip_runtime.h>
#include <math.h>

static constexpr float EPSV = 1e-5f;

// workspace float offsets
static constexpr int WS_SUM = 0;     // [0]=sum t, [1]=sum t^2
static constexpr int WS_M   = 16;    // 9 * 65 moment sums (10 M1 + 55 upper-tri M2 per p)
static constexpr int WS_A1  = 640;   // 90
static constexpr int WS_C1  = 736;   // 90
static constexpr int WS_A2  = 832;   // 270
static constexpr int WS_B2  = 1152;  // 270
static constexpr int WS_S   = 1536;  // N node sums

// 4-byte-aligned vector types: lets the backend emit global_load_dwordx4/x2
// for per-edge rows whose base is only dword-aligned (e*S floats).
typedef float f4v __attribute__((ext_vector_type(4), aligned(4), __may_alias__));
typedef float f2v __attribute__((ext_vector_type(2), aligned(4), __may_alias__));

// Load NF consecutive floats (arbitrary dword-aligned base) into registers.
// All consumption indices are compile-time constants -> stays in VGPRs.
template<int NF>
__device__ __forceinline__ void load_row(const float* __restrict__ p, float* w)
{
    #pragma unroll
    for (int i = 0; i + 4 <= NF; i += 4) {
        f4v v = *(const f4v*)(p + i);
        w[i+0] = v[0]; w[i+1] = v[1]; w[i+2] = v[2]; w[i+3] = v[3];
    }
    constexpr int base = NF & ~3;
    if constexpr ((NF & 3) == 1) {
        w[base] = p[base];
    } else if constexpr ((NF & 3) == 2) {
        f2v v = *(const f2v*)(p + base);
        w[base] = v[0]; w[base+1] = v[1];
    } else if constexpr ((NF & 3) == 3) {
        f2v v = *(const f2v*)(p + base);
        w[base] = v[0]; w[base+1] = v[1]; w[base+2] = p[base+2];
    }
}

// ---------------- pass 1: dist mean/var ----------------
__global__ __launch_bounds__(256) void k_dist_stats(const float* __restrict__ dist, int E,
                                                    float* __restrict__ ws)
{
    float s = 0.f, s2 = 0.f;
    for (int i = blockIdx.x * blockDim.x + threadIdx.x; i < E; i += gridDim.x * blockDim.x) {
        float t = dist[i];
        s += t;
        s2 = fmaf(t, t, s2);
    }
    for (int off = 32; off > 0; off >>= 1) {
        s  += __shfl_down(s, off);
        s2 += __shfl_down(s2, off);
    }
    __shared__ float ls[4], ls2[4];
    int wave = threadIdx.x >> 6, lane = threadIdx.x & 63;
    if (lane == 0) { ls[wave] = s; ls2[wave] = s2; }
    __syncthreads();
    if (threadIdx.x == 0) {
        atomicAdd(&ws[WS_SUM + 0], ls[0] + ls[1] + ls[2] + ls[3]);
        atomicAdd(&ws[WS_SUM + 1], ls2[0] + ls2[1] + ls2[2] + ls2[3]);
    }
}

// ---------------- fold layer-1 BN into affine (b1 cancels) ----------------
__global__ void k_prep1(const float* __restrict__ rW1, const float* __restrict__ rg1,
                        const float* __restrict__ rbb1, int E, float* __restrict__ ws)
{
    int idx = threadIdx.x;
    if (idx >= 90) return;
    float invE = 1.f / (float)E;
    float md = ws[WS_SUM + 0] * invE;
    float vd = ws[WS_SUM + 1] * invE - md * md;
    float w  = rW1[idx];                 // rW1 is (9,10,1)
    float a  = w * rsqrtf(w * w * vd + EPSV) * rg1[idx];
    float c  = rbb1[idx] - md * a;
    ws[WS_A1 + idx] = a;
    ws[WS_C1 + idx] = c;
}

// ---------------- pass 2: h1 first/second moments per p ----------------
__global__ __launch_bounds__(256) void k_moments(const float* __restrict__ dist, int E,
                                                 float* __restrict__ ws)
{
    int p = blockIdx.y;
    float a1[10], c1[10];
    #pragma unroll
    for (int j = 0; j < 10; j++) { a1[j] = ws[WS_A1 + p*10 + j]; c1[j] = ws[WS_C1 + p*10 + j]; }
    float M[65];
    #pragma unroll
    for (int i = 0; i < 65; i++) M[i] = 0.f;
    for (int e = blockIdx.x * blockDim.x + threadIdx.x; e < E; e += gridDim.x * blockDim.x) {
        float t = dist[e];
        float h[10];
        #pragma unroll
        for (int j = 0; j < 10; j++) h[j] = fmaxf(fmaf(a1[j], t, c1[j]), 0.f);
        #pragma unroll
        for (int j = 0; j < 10; j++) M[j] += h[j];
        int c = 10;
        #pragma unroll
        for (int j = 0; j < 10; j++)
            #pragma unroll
            for (int j2 = j; j2 < 10; j2++) {
                M[c] = fmaf(h[j], h[j2], M[c]);
                c++;
            }
    }
    #pragma unroll
    for (int i = 0; i < 65; i++) {
        float v = M[i];
        for (int off = 32; off > 0; off >>= 1) v += __shfl_down(v, off);
        M[i] = v;
    }
    __shared__ float red[4][65];
    int wave = threadIdx.x >> 6, lane = threadIdx.x & 63;
    if (lane == 0) {
        #pragma unroll
        for (int i = 0; i < 65; i++) red[wave][i] = M[i];
    }
    __syncthreads();
    if (threadIdx.x < 65) {
        float v = red[0][threadIdx.x] + red[1][threadIdx.x] + red[2][threadIdx.x] + red[3][threadIdx.x];
        atomicAdd(&ws[WS_M + p*65 + threadIdx.x], v);
    }
}

// ---------------- fold layer-2 BN into affine (b2 cancels) ----------------
__global__ void k_prep2(const float* __restrict__ rW2, const float* __restrict__ rg2,
                        const float* __restrict__ rbb2, int E, float* __restrict__ ws)
{
    int idx = blockIdx.x * blockDim.x + threadIdx.x;
    if (idx >= 270) return;
    int p = idx / 30;
    float invE = 1.f / (float)E;
    float W[10];
    #pragma unroll
    for (int j = 0; j < 10; j++) W[j] = rW2[idx * 10 + j];
    float S1 = 0.f;
    #pragma unroll
    for (int j = 0; j < 10; j++) S1 = fmaf(W[j], ws[WS_M + p*65 + j] * invE, S1);
    float S2 = 0.f;
    int c = 10;
    for (int j = 0; j < 10; j++)
        for (int j2 = j; j2 < 10; j2++) {
            float coef = W[j] * W[j2] * ((j == j2) ? 1.f : 2.f);
            S2 = fmaf(coef, ws[WS_M + p*65 + c] * invE, S2);
            c++;
        }
    float var = S2 - S1 * S1;            // biased (ddof=0), matches jnp.var
    float s2 = rg2[idx] * rsqrtf(var + EPSV);
    ws[WS_A2 + idx] = s2;                // h2 = relu((W2.h1)*A2 + B2)
    ws[WS_B2 + idx] = rbb2[idx] - S1 * s2;
}

// ---------------- main edge kernel ----------------
struct SharedParams {
    const float* W2; const float* W3; const float* b3;
    const float* a1; const float* c1; const float* A2; const float* B2;
};

template<int L, int K>
__device__ __forceinline__ void do_pair(float t, const float* __restrict__ wjbase, int e,
                                        const float* fk, const SharedParams& sp,
                                        float* acc /* [2*(2L+1)] */)
{
    constexpr int P     = L * 3 + K;
    constexpr int MINKL = (K < L) ? K : L;
    constexpr int J     = 2 * MINKL + 1;
    constexpr int NK    = 2 * K + 1;
    constexpr int NL    = 2 * L + 1;
    const float* wj = wjbase + (long long)(J * NL * NK) * (long long)e;

    float h1[10];
    #pragma unroll
    for (int j = 0; j < 10; j++)
        h1[j] = fmaxf(fmaf(sp.a1[P*10 + j], t, sp.c1[P*10 + j]), 0.f);
    float h2[30];
    #pragma unroll
    for (int f = 0; f < 30; f++) {
        float z = 0.f;
        #pragma unroll
        for (int j = 0; j < 10; j++) z = fmaf(sp.W2[(P*30 + f)*10 + j], h1[j], z);
        h2[f] = fmaxf(fmaf(z, sp.A2[P*30 + f], sp.B2[P*30 + f]), 0.f);
    }
    #pragma unroll
    for (int j = 0; j < J; j++) {
        // Vectorized load of this j-slice (NL*NK contiguous floats, dword-aligned base)
        float w[NL * NK];
        load_row<NL * NK>(wj + j * NL * NK, w);

        // R[o][i] for this j; layout r = j*4 + o*2 + i  (R reshaped (E,J,C,C))
        float R00 = sp.b3[P*20 + j*4 + 0];
        float R01 = sp.b3[P*20 + j*4 + 1];
        float R10 = sp.b3[P*20 + j*4 + 2];
        float R11 = sp.b3[P*20 + j*4 + 3];
        #pragma unroll
        for (int f = 0; f < 30; f++) {
            float h = h2[f];
            R00 = fmaf(sp.W3[(P*20 + j*4 + 0)*30 + f], h, R00);
            R01 = fmaf(sp.W3[(P*20 + j*4 + 1)*30 + f], h, R01);
            R10 = fmaf(sp.W3[(P*20 + j*4 + 2)*30 + f], h, R10);
            R11 = fmaf(sp.W3[(P*20 + j*4 + 3)*30 + f], h, R11);
        }
        #pragma unroll
        for (int m = 0; m < NL; m++) {
            float v0 = 0.f, v1 = 0.f;
            #pragma unroll
            for (int n = 0; n < NK; n++) {
                float wv = w[m * NK + n];
                v0 = fmaf(wv, fk[n], v0);        // i = 0
                v1 = fmaf(wv, fk[NK + n], v1);   // i = 1
            }
            acc[0*NL + m] += R00 * v0 + R01 * v1;
            acc[1*NL + m] += R10 * v0 + R11 * v1;
        }
    }
}

__global__ __launch_bounds__(256) void k_edge(
    const int* __restrict__ dst, const float* __restrict__ dist,
    const float* __restrict__ f0, const float* __restrict__ f1, const float* __restrict__ f2,
    const float* __restrict__ wq,
    const float* __restrict__ wj00, const float* __restrict__ wj01, const float* __restrict__ wj02,
    const float* __restrict__ wj10, const float* __restrict__ wj11, const float* __restrict__ wj12,
    const float* __restrict__ wj20, const float* __restrict__ wj21, const float* __restrict__ wj22,
    const float* __restrict__ rW2, const float* __restrict__ rW3, const float* __restrict__ rb3,
    const float* __restrict__ ws, float* __restrict__ out, float* __restrict__ snode, int E)
{
    __shared__ float sW2[2700];
    __shared__ float sW3[5400];
    __shared__ float sb3[180];
    __shared__ float sa1[90], sc1[90];
    __shared__ float sA2[270], sB2[270];
    __shared__ float swq[12];
    for (int i = threadIdx.x; i < 5400; i += 256) sW3[i] = rW3[i];
    for (int i = threadIdx.x; i < 2700; i += 256) sW2[i] = rW2[i];
    for (int i = threadIdx.x; i < 180;  i += 256) sb3[i] = rb3[i];
    for (int i = threadIdx.x; i < 90;   i += 256) { sa1[i] = ws[WS_A1 + i]; sc1[i] = ws[WS_C1 + i]; }
    for (int i = threadIdx.x; i < 270;  i += 256) { sA2[i] = ws[WS_A2 + i]; sB2[i] = ws[WS_B2 + i]; }
    if (threadIdx.x < 12) swq[threadIdx.x] = wq[threadIdx.x];
    __syncthreads();

    int e = blockIdx.x * 256 + threadIdx.x;
    if (e >= E) return;

    SharedParams sp{sW2, sW3, sb3, sa1, sc1, sA2, sB2};

    float t = dist[e];
    int d = dst[e];
    float fa0[2], fa1[6], fa2[10];
    load_row<2>(f0 + d * 2, fa0);
    load_row<6>(f1 + d * 6, fa1);
    load_row<10>(f2 + d * 10, fa2);

    float total = 0.f;
    // L = 0 (kvec col 0)
    {
        float acc[2] = {0.f, 0.f};
        do_pair<0,0>(t, wj00, e, fa0, sp, acc);
        do_pair<0,1>(t, wj10, e, fa1, sp, acc);
        do_pair<0,2>(t, wj20, e, fa2, sp, acc);
        #pragma unroll
        for (int o = 0; o < 2; o++) {
            float q = swq[0 + o*2 + 0] * fa0[0] + swq[0 + o*2 + 1] * fa0[1];
            total = fmaf(q, acc[o], total);
        }
    }
    // L = 1 (kvec cols 1..3)
    {
        float acc[6] = {0,0,0,0,0,0};
        do_pair<1,0>(t, wj01, e, fa0, sp, acc);
        do_pair<1,1>(t, wj11, e, fa1, sp, acc);
        do_pair<1,2>(t, wj21, e, fa2, sp, acc);
        #pragma unroll
        for (int o = 0; o < 2; o++)
            #pragma unroll
            for (int m = 0; m < 3; m++) {
                float q = swq[4 + o*2 + 0] * fa1[m] + swq[4 + o*2 + 1] * fa1[3 + m];
                total = fmaf(q, acc[o*3 + m], total);
            }
    }
    // L = 2 (kvec cols 4..8)
    {
        float acc[10] = {0,0,0,0,0,0,0,0,0,0};
        do_pair<2,0>(t, wj02, e, fa0, sp, acc);
        do_pair<2,1>(t, wj12, e, fa1, sp, acc);
        do_pair<2,2>(t, wj22, e, fa2, sp, acc);
        #pragma unroll
        for (int o = 0; o < 2; o++)
            #pragma unroll
            for (int m = 0; m < 5; m++) {
                float q = swq[8 + o*2 + 0] * fa2[m] + swq[8 + o*2 + 1] * fa2[5 + m];
                total = fmaf(q, acc[o*5 + m], total);
            }
    }
    float ev = expf(total);
    out[e] = ev;
    atomicAdd(&snode[d], ev);
}

__global__ __launch_bounds__(256) void k_norm(const int* __restrict__ dst,
                                              const float* __restrict__ snode,
                                              float* __restrict__ out, int E)
{
    int e = blockIdx.x * 256 + threadIdx.x;
    if (e < E) out[e] = out[e] / snode[dst[e]];
}

extern "C" void kernel_launch(void* const* d_in, const int* in_sizes, int n_in,
                              void* d_out, int out_size, void* d_ws, size_t ws_size,
                              hipStream_t stream)
{
    const int*   dst  = (const int*)  d_in[1];
    const float* dist = (const float*)d_in[2];
    const float* f0   = (const float*)d_in[3];
    const float* f1   = (const float*)d_in[4];
    const float* f2   = (const float*)d_in[5];
    const float* wq   = (const float*)d_in[6];
    const float* wj00 = (const float*)d_in[7];
    const float* wj01 = (const float*)d_in[8];
    const float* wj02 = (const float*)d_in[9];
    const float* wj10 = (const float*)d_in[10];
    const float* wj11 = (const float*)d_in[11];
    const float* wj12 = (const float*)d_in[12];
    const float* wj20 = (const float*)d_in[13];
    const float* wj21 = (const float*)d_in[14];
    const float* wj22 = (const float*)d_in[15];
    const float* rW1  = (const float*)d_in[16];
    // d_in[17] = rb1 : cancels in BN
    const float* rg1  = (const float*)d_in[18];
    const float* rbb1 = (const float*)d_in[19];
    const float* rW2  = (const float*)d_in[20];
    // d_in[21] = rb2 : cancels in BN
    const float* rg2  = (const float*)d_in[22];
    const float* rbb2 = (const float*)d_in[23];
    const float* rW3  = (const float*)d_in[24];
    const float* rb3  = (const float*)d_in[25];

    int E = in_sizes[1];
    int N = in_sizes[3] / 2;

    float* ws    = (float*)d_ws;
    float* out   = (float*)d_out;
    float* snode = ws + WS_S;

    hipMemsetAsync(d_ws, 0, (size_t)(WS_S + N) * sizeof(float), stream);

    k_dist_stats<<<256, 256, 0, stream>>>(dist, E, ws);
    k_prep1<<<1, 128, 0, stream>>>(rW1, rg1, rbb1, E, ws);
    k_moments<<<dim3(64, 9), 256, 0, stream>>>(dist, E, ws);
    k_prep2<<<2, 160, 0, stream>>>(rW2, rg2, rbb2, E, ws);

    int nb = (E + 255) / 256;
    k_edge<<<nb, 256, 0, stream>>>(dst, dist, f0, f1, f2, wq,
                                   wj00, wj01, wj02, wj10, wj11, wj12,
                                   wj20, wj21, wj22,
                                   rW2, rW3, rb3, ws, out, snode, E);
    k_norm<<<nb, 256, 0, stream>>>(dst, snode, out, E);
}